// Round 6
// baseline (14488.411 us; speedup 1.0000x reference)
//
#include <hip/hip_runtime.h>
#include <math.h>

// Problem dims
#define BSZ   128
#define TLEN  256
#define NCLS  128
#define WDIM  512
#define XDIM  640       // NC + WD
#define G4    2048      // 4*UNITS

// Geometry: 8 batch-groups (XCD-local) x 32 j-tiles = 256 blocks, 512 threads
#define BT    16        // batch rows per group
#define JTS   16        // h columns per block
#define NBLK  256
#define NTHR  512
#define KCH   8         // chunk length (steps of x-projection kept in regs)

// ws layout (float offsets) — total ~750 KB (proven to fit)
#define H_OFF    0                    // 2 * 128 * 512 h double buffer
#define LOG_OFF  131072               // 3 * 128 * 128 logits triple buffer
#define W0_OFF   180224               // 2048: bias + 1e-5*colsum(W[640:768])
#define FLAG_OFF 182272               // 256 flags, stride 16 u32 (64B lines)

typedef unsigned long long ull;

// zred banks inside flat ins[]: bank*1120 + b*70 + c   (banks: 0=xp-kh0,
// 1=xp-kh1, 2=hU-kh0, 3=hU-kh1)
#define ZB(bank, b, c) ins[(bank) * 1120 + (b) * 70 + (c)]

__device__ __forceinline__ float sigmoidf_(float x) {
  return 1.0f / (1.0f + expf(-x));
}

// relaxed device-scope 16B load as 2x b64 atomics (IC-coherent, NO buffer_inv)
__device__ __forceinline__ float4 ld_dev16(const float* p) {
  const ull* q = (const ull*)p;
  ull a = __hip_atomic_load(q,     __ATOMIC_RELAXED, __HIP_MEMORY_SCOPE_AGENT);
  ull b = __hip_atomic_load(q + 1, __ATOMIC_RELAXED, __HIP_MEMORY_SCOPE_AGENT);
  float4 r;
  ((ull*)&r)[0] = a;
  ((ull*)&r)[1] = b;
  return r;
}

__global__ void setup_kernel(const float* __restrict__ W,
                             const float* __restrict__ bias,
                             float* __restrict__ ws) {
  int tid = blockIdx.x * blockDim.x + threadIdx.x;   // 64*256 = 16384 threads
  for (int i = tid; i < 3 * BSZ * NCLS; i += 64 * 256)
    ws[LOG_OFF + i] = 0.0f;
  if (tid < 4096)
    ((unsigned int*)(ws + FLAG_OFF))[tid] = 0u;
  if (tid < G4) {
    float s = 0.0f;
    #pragma unroll 4
    for (int r = 0; r < NCLS; ++r)
      s += W[(size_t)(XDIM + r) * G4 + tid];
    ws[W0_OFF + tid] = bias[tid] + 1e-5f * s;
  }
}

__global__ void __launch_bounds__(NTHR, 1)
lstm_main(const float* __restrict__ xc, const float* __restrict__ xw,
          const float* __restrict__ W,  const float* __restrict__ U,
          const float* __restrict__ bias, const float* __restrict__ Wsm,
          const float* __restrict__ bsv, int* __restrict__ out,
          float* __restrict__ ws)
{
  __shared__ float U_lds[512 * 64];   // 128 KB resident U tile [k][cc]
  __shared__ float ins[4480];         // staging 2x[16][140] / zred 4x[16][70]
                                      // / chunk Wt[64][64] / argmax scratch
  __shared__ float wsm_lds[16 * 128]; // resident Wsm tile [j][m]
  __shared__ float hl_lds[16 * 17];   // h_new tile [b][16], padded
  __shared__ int   idx_lds[BT];

  float* Wt    = ins;                  // chunk W-tile [64][64] (4096 floats)
  float* red_v = ins;                  // argmax scratch [16][33]
  int*   red_i = (int*)(ins + 528);

  const int tid = threadIdx.x;
  const int blk = blockIdx.x;
  const int grp = blk & 7;             // batch group (XCD-local heuristic)
  const int jt  = blk >> 3;            // 0..31 j-tile
  const int b0  = grp * BT;
  const int j0  = jt * JTS;

  // chunk mapping (all 512): (batch row gb, gate gg, 4-col j4, K-half kh)
  const int gb  = tid & 15;
  const int gg  = (tid >> 4) & 3;
  const int j4  = (tid >> 6) & 3;
  const int kh  = tid >> 8;                 // 0..1
  const int cc0 = gg * 16 + j4 * 4;         // LDS column in [0,64)

  // h@U GEMM mapping (tid < 128): (k-half gkh, 4-row tile bt, col-quad ct)
  const int gkh = tid >> 6;                 // 0..1
  const int bt  = (tid >> 4) & 3;           // 0..3 (rows bt*4..bt*4+3)
  const int ct  = tid & 15;                 // 0..15 col-quad
  const int mcc = (ct >> 2) * 16 + (ct & 3) * 4;        // LDS col of quad
  const int gc0 = (ct >> 2) * 512 + j0 + (ct & 3) * 4;  // global col of quad

  // staging mapping: thread = (row srow, 4-float seg sseg)
  const int srow = tid >> 5;                // 0..15
  const int sseg = tid & 31;                // 0..31

  // logits/argmax mapping: thread = (row ub, class-quad um)
  const int ub = tid >> 5;
  const int um = tid & 31;

  // update mapping (tid < 256): thread = (row vb, h-col vj)
  const int vb = (tid >> 4) & 15;
  const int vj = tid & 15;

  float* hbuf   = ws + H_OFF;
  float* logits = ws + LOG_OFF;
  unsigned int* flags = (unsigned int*)(ws + FLAG_OFF);
  unsigned int* myflag   = flags + (grp * 32 + jt) * 16;
  unsigned int* pollflag = flags + (grp * 32 + (tid & 31)) * 16;

  // Load resident U tile: U_lds[k*64 + cc] = U[k][col(cc)]
  {
    int cc  = tid & 63;
    int col = (cc >> 4) * 512 + j0 + (cc & 15);
    int k0  = tid >> 6;  // 0..7
    for (int kk = 0; kk < 64; ++kk) {
      int k = kk * 8 + k0;
      U_lds[k * 64 + cc] = U[(size_t)k * G4 + col];
    }
  }
  // Load resident Wsm tile: wsm_lds[j][m]
  {
    int row = tid >> 5, col4 = tid & 31;
    *(float4*)(&wsm_lds[row * 128 + col4 * 4]) =
        *(const float4*)(Wsm + (size_t)(j0 + row) * NCLS + col4 * 4);
  }

  // ---- chunk GEMM: xq[s] = kh-partial x-projection for (row gb, cols
  // cc0..cc0+3), steps tt0..tt0+7. W-tile in LDS (read once per chunk),
  // s4-blocked: each w4 LDS read feeds 4 steps (4x fewer LDS instrs).
  float4 xq[KCH];
  auto chunk_gemm = [&](int tt0) {
    #pragma unroll
    for (int s = 0; s < KCH; ++s) xq[s] = make_float4(0.f, 0.f, 0.f, 0.f);
    #pragma unroll 1
    for (int kt = 0; kt < 10; ++kt) {          // ten 64-deep k-tiles
      // stage W-tile [64 k][64 cols] -> Wt (2 float4 per thread)
      int id0 = tid,       k0t = id0 >> 4, cg0 = id0 & 15;
      int id1 = tid + 512, k1t = id1 >> 4, cg1 = id1 & 15;
      int col0 = (cg0 >> 2) * 512 + j0 + (cg0 & 3) * 4;
      int col1 = (cg1 >> 2) * 512 + j0 + (cg1 & 3) * 4;
      float4 wv0 = *(const float4*)(W + (size_t)(kt * 64 + k0t) * G4 + col0);
      float4 wv1 = *(const float4*)(W + (size_t)(kt * 64 + k1t) * G4 + col1);
      __syncthreads();                         // prior Wt readers done
      *(float4*)(Wt + k0t * 64 + cg0 * 4) = wv0;
      *(float4*)(Wt + k1t * 64 + cg1 * 4) = wv1;
      __syncthreads();                         // tile visible
      const float* wp = Wt + (kh * 32) * 64 + cc0;
      #pragma unroll 1
      for (int sh = 0; sh < 2; ++sh) {
        float xr0[32], xr1[32], xr2[32], xr3[32];
        {
          int tt = tt0 + sh * 4;
          const float* s0 = (kt < 2)
            ? xc + ((size_t)(b0 + gb) * TLEN + tt) * NCLS + kt * 64 + kh * 32
            : xw + ((size_t)(b0 + gb) * TLEN + tt) * WDIM + (kt * 64 - 128) + kh * 32;
          #pragma unroll
          for (int i = 0; i < 8; ++i) *(float4*)(&xr0[4*i]) = *(const float4*)(s0 + 4*i);
          const float* s1 = s0 + ((kt < 2) ? NCLS : WDIM);
          #pragma unroll
          for (int i = 0; i < 8; ++i) *(float4*)(&xr1[4*i]) = *(const float4*)(s1 + 4*i);
          const float* s2 = s1 + ((kt < 2) ? NCLS : WDIM);
          #pragma unroll
          for (int i = 0; i < 8; ++i) *(float4*)(&xr2[4*i]) = *(const float4*)(s2 + 4*i);
          const float* s3 = s2 + ((kt < 2) ? NCLS : WDIM);
          #pragma unroll
          for (int i = 0; i < 8; ++i) *(float4*)(&xr3[4*i]) = *(const float4*)(s3 + 4*i);
        }
        #pragma unroll
        for (int kk = 0; kk < 32; ++kk) {
          float4 w4 = *(const float4*)(wp + kk * 64);
          float a0 = xr0[kk], a1 = xr1[kk], a2 = xr2[kk], a3 = xr3[kk];
          float4* q = &xq[sh * 4];
          q[0].x = fmaf(a0, w4.x, q[0].x); q[0].y = fmaf(a0, w4.y, q[0].y);
          q[0].z = fmaf(a0, w4.z, q[0].z); q[0].w = fmaf(a0, w4.w, q[0].w);
          q[1].x = fmaf(a1, w4.x, q[1].x); q[1].y = fmaf(a1, w4.y, q[1].y);
          q[1].z = fmaf(a1, w4.z, q[1].z); q[1].w = fmaf(a1, w4.w, q[1].w);
          q[2].x = fmaf(a2, w4.x, q[2].x); q[2].y = fmaf(a2, w4.y, q[2].y);
          q[2].z = fmaf(a2, w4.z, q[2].z); q[2].w = fmaf(a2, w4.w, q[2].w);
          q[3].x = fmaf(a3, w4.x, q[3].x); q[3].y = fmaf(a3, w4.y, q[3].y);
          q[3].z = fmaf(a3, w4.z, q[3].z); q[3].w = fmaf(a3, w4.w, q[3].w);
        }
      }
    }
  };

  float creg = 0.0f;      // cell state: thread(<256) owns (b0+vb, j0+vj)

  __syncthreads();        // U_lds / wsm_lds ready
  chunk_gemm(0);          // steps 0..7
  __syncthreads();        // Wt readers done before ins reuse

  for (int t = 0; t < TLEN; ++t) {
    float4 xv = xq[0];
    #pragma unroll
    for (int s = 0; s < KCH - 1; ++s) xq[s] = xq[s + 1];   // shift register

    float4 acc[4];       // h@U partials (GEMM lanes, tid<128)
    acc[0] = acc[1] = acc[2] = acc[3] = make_float4(0.f, 0.f, 0.f, 0.f);
    float4 brw[4];       // bias + one-hot W row (GEMM wave 0)

    if (t == 0) {
      if (tid < 128 && gkh == 0) {
        const float4 w0 = *(const float4*)(ws + W0_OFF + gc0);
        brw[0] = brw[1] = brw[2] = brw[3] = w0;
      }
    } else {
      // ---- argmax of step t-1 logits (redundant per block) + zero rotation
      {
        const float* lsrc = logits + ((t + 2) % 3) * (BSZ * NCLS)
                          + (b0 + ub) * NCLS + um * 4;
        const float4 bb = *(const float4*)(bsv + um * 4);
        float4 lv = ld_dev16(lsrc);            // IC-coherent, no cache inv
        float bv = lv.x + bb.x; int bi = um * 4;
        if (lv.y + bb.y > bv) { bv = lv.y + bb.y; bi = um * 4 + 1; }
        if (lv.z + bb.z > bv) { bv = lv.z + bb.z; bi = um * 4 + 2; }
        if (lv.w + bb.w > bv) { bv = lv.w + bb.w; bi = um * 4 + 3; }
        red_v[ub * 33 + um] = bv; red_i[ub * 33 + um] = bi;
        // zero buf[(t+1)%3] group rows (last read at step t-1, behind barrier)
        float* lz = logits + ((t + 1) % 3) * (BSZ * NCLS) + b0 * NCLS;
        if (tid < 64)
          __hip_atomic_store(&lz[jt * 64 + tid], 0.0f,
                             __ATOMIC_RELAXED, __HIP_MEMORY_SCOPE_AGENT);
        __syncthreads();
        if (um == 0) {
          float v = red_v[ub * 33]; int vi = red_i[ub * 33];
          #pragma unroll
          for (int s = 1; s < 32; ++s) {     // first-max tie-break via idx order
            float v2 = red_v[ub * 33 + s];
            int   i2 = red_i[ub * 33 + s];
            if (v2 > v || (v2 == v && i2 < vi)) { v = v2; vi = i2; }
          }
          idx_lds[ub] = vi;
          if (jt == 0) out[(b0 + ub) * TLEN + (t - 1)] = vi;
        }
        __syncthreads();
      }
      // ---- bias + one-hot W rows (GEMM wave 0; 4 rows per lane)
      if (tid < 128 && gkh == 0) {
        const float4 b4 = *(const float4*)(bias + gc0);
        #pragma unroll
        for (int r = 0; r < 4; ++r) {
          int wr = XDIM + idx_lds[bt * 4 + r];
          const float4 w4 = *(const float4*)(W + (size_t)wr * G4 + gc0);
          brw[r] = make_float4(b4.x + w4.x, b4.y + w4.y,
                               b4.z + w4.z, b4.w + w4.w);
        }
      }
      // ---- h @ U: 4 staged chunks, ping-pong; GEMM wave w eats chunks 2w,2w+1
      {
        const float* hprev = hbuf + ((t + 1) & 1) * (BSZ * 512);
        float4 hreg = ld_dev16(hprev + (size_t)(b0 + srow) * 512 + sseg * 4);
        *(float4*)(&ins[srow * 140 + sseg * 4]) = hreg;
        __syncthreads();
        #pragma unroll 1
        for (int ch = 0; ch < 4; ++ch) {
          float4 hnext;
          if (ch + 1 < 4)
            hnext = ld_dev16(hprev + (size_t)(b0 + srow) * 512
                             + (ch + 1) * 128 + sseg * 4);
          if (tid < 128 && gkh == (ch >> 1)) {
            const float* bp = &ins[(ch & 1) * 2240];
            const float* up = &U_lds[(ch * 128) * 64 + mcc];
            #pragma unroll 4
            for (int kk4 = 0; kk4 < 32; ++kk4) {
              float4 a0 = *(const float4*)(bp + (bt * 4 + 0) * 140 + kk4 * 4);
              float4 a1 = *(const float4*)(bp + (bt * 4 + 1) * 140 + kk4 * 4);
              float4 a2 = *(const float4*)(bp + (bt * 4 + 2) * 140 + kk4 * 4);
              float4 a3 = *(const float4*)(bp + (bt * 4 + 3) * 140 + kk4 * 4);
              const float* u = up + kk4 * 256;
              float4 u0 = *(const float4*)(u);
              float4 u1 = *(const float4*)(u + 64);
              float4 u2 = *(const float4*)(u + 128);
              float4 u3 = *(const float4*)(u + 192);
              acc[0].x = fmaf(a0.x,u0.x,fmaf(a0.y,u1.x,fmaf(a0.z,u2.x,fmaf(a0.w,u3.x,acc[0].x))));
              acc[0].y = fmaf(a0.x,u0.y,fmaf(a0.y,u1.y,fmaf(a0.z,u2.y,fmaf(a0.w,u3.y,acc[0].y))));
              acc[0].z = fmaf(a0.x,u0.z,fmaf(a0.y,u1.z,fmaf(a0.z,u2.z,fmaf(a0.w,u3.z,acc[0].z))));
              acc[0].w = fmaf(a0.x,u0.w,fmaf(a0.y,u1.w,fmaf(a0.z,u2.w,fmaf(a0.w,u3.w,acc[0].w))));
              acc[1].x = fmaf(a1.x,u0.x,fmaf(a1.y,u1.x,fmaf(a1.z,u2.x,fmaf(a1.w,u3.x,acc[1].x))));
              acc[1].y = fmaf(a1.x,u0.y,fmaf(a1.y,u1.y,fmaf(a1.z,u2.y,fmaf(a1.w,u3.y,acc[1].y))));
              acc[1].z = fmaf(a1.x,u0.z,fmaf(a1.y,u1.z,fmaf(a1.z,u2.z,fmaf(a1.w,u3.z,acc[1].z))));
              acc[1].w = fmaf(a1.x,u0.w,fmaf(a1.y,u1.w,fmaf(a1.z,u2.w,fmaf(a1.w,u3.w,acc[1].w))));
              acc[2].x = fmaf(a2.x,u0.x,fmaf(a2.y,u1.x,fmaf(a2.z,u2.x,fmaf(a2.w,u3.x,acc[2].x))));
              acc[2].y = fmaf(a2.x,u0.y,fmaf(a2.y,u1.y,fmaf(a2.z,u2.y,fmaf(a2.w,u3.y,acc[2].y))));
              acc[2].z = fmaf(a2.x,u0.z,fmaf(a2.y,u1.z,fmaf(a2.z,u2.z,fmaf(a2.w,u3.z,acc[2].z))));
              acc[2].w = fmaf(a2.x,u0.w,fmaf(a2.y,u1.w,fmaf(a2.z,u2.w,fmaf(a2.w,u3.w,acc[2].w))));
              acc[3].x = fmaf(a3.x,u0.x,fmaf(a3.y,u1.x,fmaf(a3.z,u2.x,fmaf(a3.w,u3.x,acc[3].x))));
              acc[3].y = fmaf(a3.x,u0.y,fmaf(a3.y,u1.y,fmaf(a3.z,u2.y,fmaf(a3.w,u3.y,acc[3].y))));
              acc[3].z = fmaf(a3.x,u0.z,fmaf(a3.y,u1.z,fmaf(a3.z,u2.z,fmaf(a3.w,u3.z,acc[3].z))));
              acc[3].w = fmaf(a3.x,u0.w,fmaf(a3.y,u1.w,fmaf(a3.z,u2.w,fmaf(a3.w,u3.w,acc[3].w))));
            }
          }
          if (ch + 1 < 4)
            *(float4*)(&ins[((ch + 1) & 1) * 2240 + srow * 140 + sseg * 4]) = hnext;
          __syncthreads();
        }
      }
    }

    // ---- z exchange into 4 zred banks (ins reused; staging done)
    if (t == 0) __syncthreads();   // align sync count for t==0 path
    *(float4*)(&ZB(kh, gb, cc0)) = xv;                     // xp partial (all)
    if (tid < 128) {
      if (gkh == 0) {
        #pragma unroll
        for (int r = 0; r < 4; ++r) {
          acc[r].x += brw[r].x; acc[r].y += brw[r].y;
          acc[r].z += brw[r].z; acc[r].w += brw[r].w;
        }
      }
      #pragma unroll
      for (int r = 0; r < 4; ++r)
        *(float4*)(&ZB(2 + gkh, bt * 4 + r, mcc)) = acc[r];
    }
    __syncthreads();

    // ---- gate nonlinearities + cell/hidden update (first 256 threads)
    if (tid < 256) {
      float zi = ZB(0,vb, 0+vj) + ZB(1,vb, 0+vj) + ZB(2,vb, 0+vj) + ZB(3,vb, 0+vj);
      float zf = ZB(0,vb,16+vj) + ZB(1,vb,16+vj) + ZB(2,vb,16+vj) + ZB(3,vb,16+vj);
      float zg = ZB(0,vb,32+vj) + ZB(1,vb,32+vj) + ZB(2,vb,32+vj) + ZB(3,vb,32+vj);
      float zo = ZB(0,vb,48+vj) + ZB(1,vb,48+vj) + ZB(2,vb,48+vj) + ZB(3,vb,48+vj);
      float iv = sigmoidf_(zi);
      float fv = sigmoidf_(zf);
      float gv = tanhf(zg);
      float ov = sigmoidf_(zo);
      creg = fv * creg + iv * gv;
      float hn = ov * tanhf(creg);
      __hip_atomic_store(hbuf + (t & 1) * (BSZ * 512)
                         + (size_t)(b0 + vb) * 512 + j0 + vj, hn,
                         __ATOMIC_RELAXED, __HIP_MEMORY_SCOPE_AGENT);
      hl_lds[vb * 17 + vj] = hn;
    }
    __syncthreads();

    // ---- logits partial over this block's 16 j, atomic into buf[t%3]
    {
      float p0 = 0.f, p1 = 0.f, p2 = 0.f, p3 = 0.f;
      #pragma unroll
      for (int j = 0; j < 16; ++j) {
        float hv = hl_lds[ub * 17 + j];
        const float4 wv = *(const float4*)(&wsm_lds[j * 128 + um * 4]);
        p0 = fmaf(hv, wv.x, p0); p1 = fmaf(hv, wv.y, p1);
        p2 = fmaf(hv, wv.z, p2); p3 = fmaf(hv, wv.w, p3);
      }
      float* ld = logits + (t % 3) * (BSZ * NCLS)
                + (size_t)(b0 + ub) * NCLS + um * 4;
      atomicAdd(ld + 0, p0); atomicAdd(ld + 1, p1);
      atomicAdd(ld + 2, p2); atomicAdd(ld + 3, p3);
    }

    // ---- group barrier: relaxed flags only (no wbl2/inv); syncthreads
    // drains vmcnt so h stores / logit atomics are IC-visible first.
    __syncthreads();
    if (tid == 0)
      __hip_atomic_store(myflag, (unsigned)(t + 1),
                         __ATOMIC_RELAXED, __HIP_MEMORY_SCOPE_AGENT);
    if (((t + 1) & (KCH - 1)) == 0 && t + 1 < TLEN)
      chunk_gemm(t + 1);                // heavy, recurrence-independent work
    if (tid < 64) {
      const unsigned tgt = (unsigned)(t + 1);
      for (;;) {
        unsigned v = __hip_atomic_load(pollflag, __ATOMIC_RELAXED,
                                       __HIP_MEMORY_SCOPE_AGENT);
        if (__all(v >= tgt)) break;
        __builtin_amdgcn_s_sleep(1);
      }
    }
    __syncthreads();
  }

  // ---- epilogue: argmax for final step (buf (TLEN-1)%3 == 0)
  if (jt == 0) {
    const float* lsrc = logits + ((TLEN - 1) % 3) * (BSZ * NCLS)
                      + (b0 + ub) * NCLS + um * 4;
    const float4 bb = *(const float4*)(bsv + um * 4);
    float4 lv = ld_dev16(lsrc);
    float bv = lv.x + bb.x; int bi = um * 4;
    if (lv.y + bb.y > bv) { bv = lv.y + bb.y; bi = um * 4 + 1; }
    if (lv.z + bb.z > bv) { bv = lv.z + bb.z; bi = um * 4 + 2; }
    if (lv.w + bb.w > bv) { bv = lv.w + bb.w; bi = um * 4 + 3; }
    __syncthreads();
    red_v[ub * 33 + um] = bv; red_i[ub * 33 + um] = bi;
    __syncthreads();
    if (um == 0) {
      float v = red_v[ub * 33]; int vi = red_i[ub * 33];
      #pragma unroll
      for (int s = 1; s < 32; ++s) {
        float v2 = red_v[ub * 33 + s];
        int   i2 = red_i[ub * 33 + s];
        if (v2 > v || (v2 == v && i2 < vi)) { v = v2; vi = i2; }
      }
      out[(b0 + ub) * TLEN + (TLEN - 1)] = vi;
    }
  }
}

extern "C" void kernel_launch(void* const* d_in, const int* in_sizes, int n_in,
                              void* d_out, int out_size, void* d_ws, size_t ws_size,
                              hipStream_t stream) {
  (void)in_sizes; (void)n_in; (void)out_size; (void)ws_size;
  const float* xc  = (const float*)d_in[0];
  const float* xw  = (const float*)d_in[1];
  const float* W   = (const float*)d_in[2];
  const float* U   = (const float*)d_in[3];
  const float* b   = (const float*)d_in[4];
  const float* Wsm = (const float*)d_in[5];
  const float* bs  = (const float*)d_in[6];
  int*   out = (int*)d_out;
  float* ws  = (float*)d_ws;

  hipLaunchKernelGGL(setup_kernel, dim3(64), dim3(256), 0, stream, W, b, ws);

  void* args[] = { (void*)&xc, (void*)&xw, (void*)&W, (void*)&U, (void*)&b,
                   (void*)&Wsm, (void*)&bs, (void*)&out, (void*)&ws };
  hipLaunchCooperativeKernel((const void*)lstm_main, dim3(NBLK), dim3(NTHR),
                             args, 0, stream);
}